// Round 2
// baseline (190.706 us; speedup 1.0000x reference)
//
#include <hip/hip_runtime.h>

#define H 65536
#define CIN 64
#define COUT 128
#define NK 27
#define KTOT (NK*CIN)   // 1728
#define NB 128          // points per block in conv kernel
#define NTHR 512        // 8 waves

typedef unsigned short u16;
typedef unsigned int   u32;
typedef __attribute__((ext_vector_type(8))) short short8;   // 8 bf16 = 4 VGPRs (MFMA frag)
typedef __attribute__((ext_vector_type(4))) float f32x4;    // MFMA acc
typedef __attribute__((ext_vector_type(4))) unsigned int u32x4; // 16B vector

__device__ __forceinline__ u16 f2bf(float f) {
    u32 u = __float_as_uint(f);
    u = (u + 0x7FFFu + ((u >> 16) & 1u)) >> 16;   // RNE
    return (u16)u;
}

// ---------------------------------------------------------------------------
// Kernel 1a: x (64 x 65536 f32, c-major) -> x_t (65536 x 64 bf16, point-major)
__global__ __launch_bounds__(256) void transpose_x(const float* __restrict__ x,
                                                   u16* __restrict__ xt) {
    const int h = blockIdx.x * 256 + threadIdx.x;
    u32 pk[32];
#pragma unroll
    for (int cp = 0; cp < 32; ++cp) {
        float f0 = x[(2 * cp)     * H + h];
        float f1 = x[(2 * cp + 1) * H + h];
        pk[cp] = (u32)f2bf(f0) | ((u32)f2bf(f1) << 16);
    }
    u32x4* dst = (u32x4*)(xt + (size_t)h * CIN);
#pragma unroll
    for (int i = 0; i < 8; ++i)
        dst[i] = *(u32x4*)&pk[i * 4];
}

// ---------------------------------------------------------------------------
// Kernel 1b: w (128 x 64 x 27 f32) -> wb[o][k*64+c] bf16. Also zeroes BN sums.
__global__ __launch_bounds__(256) void conv_w(const float* __restrict__ w,
                                              u16* __restrict__ wb,
                                              float* __restrict__ sums) {
    const int tid = blockIdx.x * 256 + threadIdx.x;
    if (blockIdx.x == 0) sums[threadIdx.x] = 0.f;   // 256 floats: sum[128], sumsq[128]
    if (tid < COUT * KTOT) {
        const int o = tid / KTOT;
        const int rem = tid - o * KTOT;
        const int k = rem >> 6;
        const int c = rem & 63;
        wb[tid] = f2bf(w[o * KTOT + c * NK + k]);
    }
}

// ---------------------------------------------------------------------------
// Kernel 2: fused gather + GEMM + BN partial sums.
// Block: 512 thr = 8 waves (4 o-groups x 2 n-groups). Tile: 128 o x 128 points.
// Double-buffered LDS B, 2-deep register gather prefetch, ONE barrier per k.
__global__ __launch_bounds__(NTHR, 4) void conv_mfma(const u16* __restrict__ xt,
                                                     const u16* __restrict__ wb,
                                                     const int* __restrict__ neigh,
                                                     float* __restrict__ out,
                                                     float* __restrict__ sums) {
    __shared__ __align__(16) u16 sB[2][NB * CIN];   // 2 x 16 KB, XOR-swizzled 16B slots
    __shared__ int sIdx[NB * NK];                   // 13824 B

    const int tid  = threadIdx.x;
    const int lane = tid & 63;
    const int w    = tid >> 6;        // wave 0..7
    const int wo   = w >> 1;          // o-group 0..3 (32 o each)
    const int wn   = w & 1;           // n-group 0..1 (64 n each)
    const int n0   = blockIdx.x * NB;

    for (int i = tid; i < NB * NK; i += NTHR)
        sIdx[i] = neigh[n0 * NK + i];
    __syncthreads();

    f32x4 acc[2][4] = {};             // [o-frag][n-frag], each 16x16

    // staging: lane covers point p = w*16 + it*8 + (lane>>3), 16B slot s = lane&7
    const int pbase = w * 16 + (lane >> 3);
    const int s     = lane & 7;
    const int ro    = lane & 15;
    const int kc    = (lane >> 4) * 8;

    u32x4 rgA[2], rgB[2];
#pragma unroll
    for (int it = 0; it < 2; ++it) {
        const int p = pbase + it * 8;
        rgA[it] = *(const u32x4*)(xt + (size_t)sIdx[p * NK + 0] * CIN + s * 8);
        rgB[it] = *(const u32x4*)(xt + (size_t)sIdx[p * NK + 1] * CIN + s * 8);
    }
    // write k=0 into sB[0]
#pragma unroll
    for (int it = 0; it < 2; ++it) {
        const int p = pbase + it * 8;
        *(u32x4*)(&sB[0][p * CIN + (s ^ (p & 7)) * 8]) = rgA[it];
    }
    __syncthreads();

    // BODY(k): MFMA on sB[k&1]; write WR (gather k+1) -> sB[(k&1)^1];
    //          issue gather k+2 -> LD; one barrier.
#define BODY(K, WR, LD)                                                          \
    {                                                                            \
        const int k_ = (K);                                                      \
        const int cur_ = k_ & 1;                                                 \
        short8 afr[2][2];                                                        \
        _Pragma("unroll")                                                        \
        for (int hh = 0; hh < 2; ++hh)                                           \
            _Pragma("unroll")                                                    \
            for (int f = 0; f < 2; ++f) {                                        \
                const int o = wo * 32 + f * 16 + ro;                             \
                afr[hh][f] = *(const short8*)(wb + (size_t)o * KTOT +            \
                                              k_ * CIN + hh * 32 + kc);          \
            }                                                                    \
        _Pragma("unroll")                                                        \
        for (int hh = 0; hh < 2; ++hh) {                                         \
            short8 bfr[4];                                                       \
            _Pragma("unroll")                                                    \
            for (int nf = 0; nf < 4; ++nf) {                                     \
                const int p = wn * 64 + nf * 16 + ro;                            \
                const int slin = hh * 4 + (lane >> 4);                           \
                bfr[nf] = *(const short8*)(&sB[cur_][p * CIN +                   \
                                           (slin ^ (p & 7)) * 8]);               \
            }                                                                    \
            _Pragma("unroll")                                                    \
            for (int f = 0; f < 2; ++f)                                          \
                _Pragma("unroll")                                                \
                for (int nf = 0; nf < 4; ++nf)                                   \
                    acc[f][nf] = __builtin_amdgcn_mfma_f32_16x16x32_bf16(        \
                        afr[hh][f], bfr[nf], acc[f][nf], 0, 0, 0);               \
        }                                                                        \
        if (k_ + 1 < NK) {                                                       \
            _Pragma("unroll")                                                    \
            for (int it = 0; it < 2; ++it) {                                     \
                const int p = pbase + it * 8;                                    \
                *(u32x4*)(&sB[cur_ ^ 1][p * CIN + (s ^ (p & 7)) * 8]) = WR[it];  \
            }                                                                    \
        }                                                                        \
        if (k_ + 2 < NK) {                                                       \
            _Pragma("unroll")                                                    \
            for (int it = 0; it < 2; ++it) {                                     \
                const int p = pbase + it * 8;                                    \
                LD[it] = *(const u32x4*)(xt +                                    \
                          (size_t)sIdx[p * NK + k_ + 2] * CIN + s * 8);          \
            }                                                                    \
        }                                                                        \
        __syncthreads();                                                         \
    }

    for (int kk = 0; kk < NK - 1; kk += 2) {
        BODY(kk, rgB, rgA)
        BODY(kk + 1, rgA, rgB)
    }
    BODY(NK - 1, rgB, rgA)   // k=26: no write, no gather
#undef BODY

    // epilogue: C/D layout: col(n) = lane&15, row(o) = (lane>>4)*4 + r
#pragma unroll
    for (int f = 0; f < 2; ++f)
#pragma unroll
        for (int nf = 0; nf < 4; ++nf)
#pragma unroll
            for (int r = 0; r < 4; ++r) {
                const int o = wo * 32 + f * 16 + (lane >> 4) * 4 + r;
                const int n = n0 + wn * 64 + nf * 16 + ro;
                out[(size_t)o * H + n] = acc[f][nf][r];
            }

    // fused BN partial sums: reduce over this wave's 64 n per o, then atomicAdd
#pragma unroll
    for (int f = 0; f < 2; ++f)
#pragma unroll
        for (int r = 0; r < 4; ++r) {
            float sv = acc[f][0][r] + acc[f][1][r] + acc[f][2][r] + acc[f][3][r];
            float sq = acc[f][0][r] * acc[f][0][r] + acc[f][1][r] * acc[f][1][r]
                     + acc[f][2][r] * acc[f][2][r] + acc[f][3][r] * acc[f][3][r];
#pragma unroll
            for (int m = 1; m < 16; m <<= 1) {
                sv += __shfl_xor(sv, m, 64);
                sq += __shfl_xor(sq, m, 64);
            }
            if (ro == 0) {
                const int o = wo * 32 + f * 16 + (lane >> 4) * 4 + r;
                atomicAdd(&sums[o], sv);
                atomicAdd(&sums[COUT + o], sq);
            }
        }
}

// ---------------------------------------------------------------------------
// Kernel 3: BN + ReLU with inline stats (sums accumulated by conv), float4.
__global__ __launch_bounds__(256) void bn_relu(float* __restrict__ out,
                                               const float* __restrict__ sums,
                                               const float* __restrict__ gamma,
                                               const float* __restrict__ beta) {
    const int idx = blockIdx.x * 256 + threadIdx.x;  // float4 index
    const int o = idx >> 14;                          // 16384 float4 per channel
    const float mean = sums[o] * (1.f / (float)H);
    const float var  = sums[COUT + o] * (1.f / (float)H) - mean * mean;
    const float a = gamma[o] * rsqrtf(var + 1e-5f);
    const float b = beta[o] - mean * a;
    float4* p = (float4*)out;
    float4 v = p[idx];
    v.x = fmaxf(fmaf(v.x, a, b), 0.f);
    v.y = fmaxf(fmaf(v.y, a, b), 0.f);
    v.z = fmaxf(fmaf(v.z, a, b), 0.f);
    v.w = fmaxf(fmaf(v.w, a, b), 0.f);
    p[idx] = v;
}

// ---------------------------------------------------------------------------
extern "C" void kernel_launch(void* const* d_in, const int* in_sizes, int n_in,
                              void* d_out, int out_size, void* d_ws, size_t ws_size,
                              hipStream_t stream) {
    const float* x     = (const float*)d_in[0];  // (1,64,65536,1)
    const int*   neigh = (const int*)d_in[1];    // (65536,27)
    const float* w     = (const float*)d_in[2];  // (128,64,27)
    const float* gamma = (const float*)d_in[3];
    const float* beta  = (const float*)d_in[4];
    float* out = (float*)d_out;                  // (1,128,65536,1)

    char* ws = (char*)d_ws;
    u16* xt = (u16*)ws;                               // 8388608 B
    u16* wb = (u16*)(ws + 8388608);                   // 442368 B
    float* sums = (float*)(ws + 8388608 + 442368);    // 256 floats

    transpose_x<<<H / 256, 256, 0, stream>>>(x, xt);
    conv_w<<<(COUT * KTOT + 255) / 256, 256, 0, stream>>>(w, wb, sums);
    conv_mfma<<<H / NB, NTHR, 0, stream>>>(xt, wb, neigh, out, sums);
    bn_relu<<<(COUT * H / 4) / 256, 256, 0, stream>>>(out, sums, gamma, beta);
}